// Round 7
// baseline (12799.264 us; speedup 1.0000x reference)
//
#include <hip/hip_runtime.h>

// ---------------------------------------------------------------------------
// PAM (parallax attention) forward, MI355X. Round 5 (fourth resubmit — rounds
// 3-6 were GPU-broker infra failures; this kernel has never been measured):
//  - convs restructured: 32x32 tile, 4 adjacent rows/thread x 16 oc
//    (acc[4][16]), overlapping 9-tap windows -> 18 xv ds_reads feed 4 px.
//  - single barrier per ic (double-buffer writes go to the other buffer;
//    one barrier orders both WAR and RAW).
//  - __launch_bounds__(256,3) -> VGPR<=168, 3 blocks/CU TLP.
//  - conv2f keeps the folded 1x1 (16 outputs) + cat residual, same structure.
//
// Workspace (floats) — unchanged:
//   [0, 33554432)        y1 ; later aliased GK@0, GQ@8388608, Gxr@16777216, Gxl@25165824
//   [33554432, 41943040) Q
//   [41943040, 50331648) K   (first 49216 floats used as WfQ/bfQ scratch pre-K)
//   [50331648, 50332672) bn stats: [side][scale(256), shift(256)]
// d_out used as scratch for WfK/bfK until k_attn writes it.
// ---------------------------------------------------------------------------

__global__ __launch_bounds__(256) void k_bnstats(
    const float* __restrict__ cat_l, const float* __restrict__ cat_r,
    const float* __restrict__ gamma, const float* __restrict__ beta,
    float* __restrict__ stats)
{
    int ch = blockIdx.x & 255;
    int side = blockIdx.x >> 8;
    const float* src = side ? cat_r : cat_l;
    int tid = threadIdx.x;
    float s = 0.f, s2 = 0.f;
    #pragma unroll
    for (int b = 0; b < 2; ++b) {
        const float* p = src + (size_t)b * 16777216 + (size_t)ch * 65536;
        for (int i = tid; i < 65536; i += 256) {
            float v = p[i];
            s += v; s2 += v * v;
        }
    }
    __shared__ float rs[256], rq[256];
    rs[tid] = s; rq[tid] = s2;
    __syncthreads();
    for (int off = 128; off > 0; off >>= 1) {
        if (tid < off) { rs[tid] += rs[tid + off]; rq[tid] += rq[tid + off]; }
        __syncthreads();
    }
    if (tid == 0) {
        float mean = rs[0] * (1.f / 131072.f);
        float var  = rq[0] * (1.f / 131072.f) - mean * mean;
        float rstd = rsqrtf(var + 1e-5f);
        float sc = gamma[ch] * rstd;
        stats[side * 512 + ch] = sc;
        stats[side * 512 + 256 + ch] = beta[ch] - mean * sc;
    }
}

// Fold grouped 1x1 (pw,pb) into conv2 3x3 weights + BN residual.
// Wf layout: [(g*64+ic)*16 + j] * 12 : [0..8]=Wtilde, [9]=pw[j][ic]*sc[ic], pad.
__global__ __launch_bounds__(256) void k_fold(
    const float* __restrict__ w2, const float* __restrict__ b2,
    const float* __restrict__ bqw, const float* __restrict__ bqb,
    const float* __restrict__ bsw, const float* __restrict__ bsb,
    const float* __restrict__ stats,
    float* __restrict__ WfQ, float* __restrict__ bfQ,
    float* __restrict__ WfK, float* __restrict__ bfK)
{
    int idx = blockIdx.x * 256 + threadIdx.x;
    int j    = idx & 15;
    int ic   = (idx >> 4) & 63;
    int g    = (idx >> 10) & 3;
    int side = (idx >> 12) & 1;
    const float* pw  = side ? bsw : bqw;
    const float* st  = stats + side * 512;
    const float* pwr = pw + (size_t)(g * 16 + j) * 64;
    const float* wbase = w2 + (size_t)(g * 64) * 576 + ic * 9;
    float a[9] = {0.f,0.f,0.f,0.f,0.f,0.f,0.f,0.f,0.f};
    #pragma unroll 4
    for (int oc = 0; oc < 64; ++oc) {
        float p = pwr[oc];
        const float* wrow = wbase + (size_t)oc * 576;
        #pragma unroll
        for (int k = 0; k < 9; ++k) a[k] = fmaf(p, wrow[k], a[k]);
    }
    float* dst = (side ? WfK : WfQ) + (size_t)((g * 64 + ic) * 16 + j) * 12;
    #pragma unroll
    for (int k = 0; k < 9; ++k) dst[k] = a[k];
    dst[9]  = pwr[ic] * st[g * 64 + ic];
    dst[10] = 0.f; dst[11] = 0.f;
    if (ic == 0) {
        float s = (side ? bsb : bqb)[g * 16 + j];
        for (int oc = 0; oc < 64; ++oc)
            s = fmaf(pwr[oc], b2[g * 64 + oc] + st[256 + g * 64 + oc], s);
        (side ? bfK : bfQ)[g * 16 + j] = s;
    }
}

// Grouped 3x3 conv (BN on the fly), bias + LeakyReLU(0.1).
// 32x32 tile, 4 adjacent rows/thread, 16 oc/block (oh quarter).
__global__ __launch_bounds__(256, 3) void k_conv1(
    const float* __restrict__ cat, const float* __restrict__ stats,
    const float* __restrict__ w1, const float* __restrict__ b1,
    float* __restrict__ y1)
{
    int blk = blockIdx.x;
    int wt = blk & 7;   blk >>= 3;
    int ht = blk & 7;   blk >>= 3;
    int oh = blk & 3;   blk >>= 2;
    int g  = blk & 3;   blk >>= 2;
    int b  = blk;
    int tid = threadIdx.x;
    int tw = tid & 31, th = tid >> 5;   // th 0..7
    int rb = th * 4;                    // local row base: rows rb..rb+3
    int h = ht * 32 + rb, w = wt * 32 + tw;

    __shared__ __align__(16) float tile[2][34][36];
    __shared__ __align__(16) float wb[2][16][12];

    float acc[4][16];
    #pragma unroll
    for (int j = 0; j < 16; ++j) {
        float bb = b1[g * 64 + oh * 16 + j];
        acc[0][j] = bb; acc[1][j] = bb; acc[2][j] = bb; acc[3][j] = bb;
    }

    const float* catg = cat + ((size_t)b * 256 + g * 64) * 65536;
    const float* wg = w1 + (size_t)(g * 64 + oh * 16) * 576;
    int h0 = ht * 32 - 1, w0 = wt * 32 - 1;

    // staging geometry: 34x34 = 1156 elements, 5 slots/thread
    int soff[5]; int slds[5]; bool sin[5];
    #pragma unroll
    for (int s = 0; s < 5; ++s) {
        int idx = tid + 256 * s;
        int r = idx / 34, c = idx - r * 34;
        bool v = idx < 1156;
        int hh = h0 + r, ww = w0 + c;
        sin[s]  = v && (unsigned)hh < 256u && (unsigned)ww < 256u;
        soff[s] = hh * 256 + ww;
        slds[s] = v ? (r * 36 + c) : (33 * 36 + 35); // park OOB slots on a pad cell
    }
    // weight staging: 16 oc x 9 = 144, 1 slot/thread
    bool wvld = tid < 144;
    int woc = tid / 9, wk = tid - woc * 9;
    const float* wptr = wg + (size_t)woc * 576 + wk;
    int wlds = woc * 12 + wk;

    float t[5], wv, csn, shn;
    float* tile0 = &tile[0][0][0];
    float* wb0 = &wb[0][0][0];

    {   // prologue: stage ic=0 into buffer 0
        csn = stats[g * 64]; shn = stats[256 + g * 64];
        #pragma unroll
        for (int s = 0; s < 5; ++s) {
            t[s] = sin[s] ? catg[soff[s]] : 0.f;
            tile0[slds[s]] = sin[s] ? fmaf(t[s], csn, shn) : 0.f;
        }
        if (wvld) wb0[wlds] = wptr[0];
    }
    __syncthreads();

    int cur = 0;
    for (int ic = 0; ic < 64; ++ic) {
        bool pf = (ic + 1 < 64);
        if (pf) {   // issue next-ic loads early
            const float* plane = catg + (size_t)(ic + 1) * 65536;
            csn = stats[g * 64 + ic + 1];
            shn = stats[256 + g * 64 + ic + 1];
            #pragma unroll
            for (int s = 0; s < 5; ++s) t[s] = sin[s] ? plane[soff[s]] : 0.f;
            wv = wvld ? wptr[(ic + 1) * 9] : 0.f;
        }
        float xr[6][3];
        #pragma unroll
        for (int rr = 0; rr < 6; ++rr)
            #pragma unroll
            for (int cc = 0; cc < 3; ++cc)
                xr[rr][cc] = tile[cur][rb + rr][tw + cc];
        #pragma unroll
        for (int j = 0; j < 16; ++j) {
            float4 wa = *(const float4*)&wb[cur][j][0];
            float4 wc = *(const float4*)&wb[cur][j][4];
            float w8  = wb[cur][j][8];
            #pragma unroll
            for (int i = 0; i < 4; ++i) {
                float s = acc[i][j];
                s = fmaf(wa.x, xr[i    ][0], s);
                s = fmaf(wa.y, xr[i    ][1], s);
                s = fmaf(wa.z, xr[i    ][2], s);
                s = fmaf(wa.w, xr[i + 1][0], s);
                s = fmaf(wc.x, xr[i + 1][1], s);
                s = fmaf(wc.y, xr[i + 1][2], s);
                s = fmaf(wc.z, xr[i + 2][0], s);
                s = fmaf(wc.w, xr[i + 2][1], s);
                s = fmaf(w8,   xr[i + 2][2], s);
                acc[i][j] = s;
            }
        }
        if (pf) {   // write OTHER buffer: no barrier needed before writes
            float* tn = &tile[cur ^ 1][0][0];
            #pragma unroll
            for (int s = 0; s < 5; ++s)
                tn[slds[s]] = sin[s] ? fmaf(t[s], csn, shn) : 0.f;
            if (wvld) (&wb[cur ^ 1][0][0])[wlds] = wv;
        }
        __syncthreads();   // single barrier: orders RAW (nb) and WAR (cur)
        cur ^= 1;
    }

    float* yp = y1 + ((size_t)b * 256 + g * 64 + oh * 16) * 65536
                   + (size_t)h * 256 + w;
    #pragma unroll
    for (int j = 0; j < 16; ++j)
        #pragma unroll
        for (int i = 0; i < 4; ++i) {
            float v = acc[i][j];
            yp[(size_t)j * 65536 + i * 256] = v > 0.f ? v : 0.1f * v;
        }
}

// Folded conv2: 16 outputs per group (Wtilde 3x3 over y1 + pwsc*cat residual).
// Same 32x32 / 4-row / single-barrier structure.
__global__ __launch_bounds__(256, 3) void k_conv2f(
    const float* __restrict__ y1, const float* __restrict__ cat,
    const float* __restrict__ Wf, const float* __restrict__ bf,
    float* __restrict__ Qout)
{
    int blk = blockIdx.x;
    int wt = blk & 7;   blk >>= 3;
    int ht = blk & 7;   blk >>= 3;
    int g  = blk & 3;   blk >>= 2;
    int b  = blk;
    int tid = threadIdx.x;
    int tw = tid & 31, th = tid >> 5;
    int rb = th * 4;
    int h = ht * 32 + rb, w = wt * 32 + tw;

    __shared__ __align__(16) float tile[2][34][36];
    __shared__ __align__(16) float wb[2][16][12];

    float acc[4][16];
    #pragma unroll
    for (int j = 0; j < 16; ++j) {
        float bb = bf[g * 16 + j];
        acc[0][j] = bb; acc[1][j] = bb; acc[2][j] = bb; acc[3][j] = bb;
    }

    const float* yg = y1 + ((size_t)b * 256 + g * 64) * 65536;
    const float* catp = cat + ((size_t)b * 256 + g * 64) * 65536
                            + (size_t)h * 256 + w;
    const float* wfg = Wf + (size_t)(g * 64) * 192;
    int h0 = ht * 32 - 1, w0 = wt * 32 - 1;

    int soff[5]; int slds[5]; bool sin[5];
    #pragma unroll
    for (int s = 0; s < 5; ++s) {
        int idx = tid + 256 * s;
        int r = idx / 34, c = idx - r * 34;
        bool v = idx < 1156;
        int hh = h0 + r, ww = w0 + c;
        sin[s]  = v && (unsigned)hh < 256u && (unsigned)ww < 256u;
        soff[s] = hh * 256 + ww;
        slds[s] = v ? (r * 36 + c) : (33 * 36 + 35);
    }
    bool wvld = tid < 192;   // 16 j x 12
    float t[5], wv, cv[4], ncv[4];
    float* tile0 = &tile[0][0][0];

    {   // prologue ic=0
        #pragma unroll
        for (int s = 0; s < 5; ++s) {
            t[s] = sin[s] ? yg[soff[s]] : 0.f;
            tile0[slds[s]] = t[s];
        }
        if (wvld) (&wb[0][0][0])[tid] = wfg[tid];
        #pragma unroll
        for (int i = 0; i < 4; ++i) cv[i] = catp[i * 256];
    }
    __syncthreads();

    int cur = 0;
    for (int ic = 0; ic < 64; ++ic) {
        bool pf = (ic + 1 < 64);
        if (pf) {
            const float* plane = yg + (size_t)(ic + 1) * 65536;
            #pragma unroll
            for (int s = 0; s < 5; ++s) t[s] = sin[s] ? plane[soff[s]] : 0.f;
            wv = wvld ? wfg[(size_t)(ic + 1) * 192 + tid] : 0.f;
            #pragma unroll
            for (int i = 0; i < 4; ++i)
                ncv[i] = catp[(size_t)(ic + 1) * 65536 + i * 256];
        }
        float xr[6][3];
        #pragma unroll
        for (int rr = 0; rr < 6; ++rr)
            #pragma unroll
            for (int cc = 0; cc < 3; ++cc)
                xr[rr][cc] = tile[cur][rb + rr][tw + cc];
        #pragma unroll
        for (int j = 0; j < 16; ++j) {
            float4 wa = *(const float4*)&wb[cur][j][0];
            float4 wc = *(const float4*)&wb[cur][j][4];
            float4 wd = *(const float4*)&wb[cur][j][8];  // x=w8, y=pws
            #pragma unroll
            for (int i = 0; i < 4; ++i) {
                float s = acc[i][j];
                s = fmaf(wa.x, xr[i    ][0], s);
                s = fmaf(wa.y, xr[i    ][1], s);
                s = fmaf(wa.z, xr[i    ][2], s);
                s = fmaf(wa.w, xr[i + 1][0], s);
                s = fmaf(wc.x, xr[i + 1][1], s);
                s = fmaf(wc.y, xr[i + 1][2], s);
                s = fmaf(wc.z, xr[i + 2][0], s);
                s = fmaf(wc.w, xr[i + 2][1], s);
                s = fmaf(wd.x, xr[i + 2][2], s);
                s = fmaf(wd.y, cv[i], s);
                acc[i][j] = s;
            }
        }
        if (pf) {
            float* tn = &tile[cur ^ 1][0][0];
            #pragma unroll
            for (int s = 0; s < 5; ++s) tn[slds[s]] = t[s];
            if (wvld) (&wb[cur ^ 1][0][0])[tid] = wv;
            #pragma unroll
            for (int i = 0; i < 4; ++i) cv[i] = ncv[i];
        }
        __syncthreads();
        cur ^= 1;
    }

    float* qp = Qout + ((size_t)b * 64 + g * 16) * 65536 + (size_t)h * 256 + w;
    #pragma unroll
    for (int j = 0; j < 16; ++j)
        #pragma unroll
        for (int i = 0; i < 4; ++i)
            qp[(size_t)j * 65536 + i * 256] = acc[i][j];
}

// Horizontal disparity gathers, output in [b,h,w,c] layout (flat-index ready).
__global__ __launch_bounds__(256) void k_gather(
    const float* __restrict__ Kb, const float* __restrict__ Qb,
    const float* __restrict__ xr, const float* __restrict__ xl,
    const int* __restrict__ dl, const int* __restrict__ dr,
    float* __restrict__ GK, float* __restrict__ GQ,
    float* __restrict__ Gxr, float* __restrict__ Gxl)
{
    int blk = blockIdx.x;
    int h = blk & 255; blk >>= 8;
    int b = blk & 1;   blk >>= 1;
    int sel = blk;
    const float* src; float* dst; const int* dd; int r2l;
    if (sel == 0)      { src = Kb; dst = GK;  dd = dl; r2l = 1; }
    else if (sel == 1) { src = Qb; dst = GQ;  dd = dr; r2l = 0; }
    else if (sel == 2) { src = xr; dst = Gxr; dd = dl; r2l = 1; }
    else               { src = xl; dst = Gxl; dd = dr; r2l = 0; }
    const int* drow = dd + ((size_t)b * 256 + h) * 256;
    const float* sp = src + (size_t)b * 4194304 + h * 256;
    float* dp = dst + ((size_t)b * 256 + h) * 16384;
    int tid = threadIdx.x;
    for (int i = tid; i < 16384; i += 256) {
        int w = i >> 6, cc = i & 63;
        int d = drow[w];
        int wi = r2l ? (w - d < 0 ? 0 : w - d) : (w + d > 255 ? 255 : w + d);
        dp[i] = sp[(size_t)cc * 65536 + wi];
    }
}

// Per-window attention: score = patchA @ centered(sel)^T, softmax, @ x_sel,
// unpatchify + masked residual. One block per (dir, b, hn, wn).
__global__ __launch_bounds__(256) void k_attn(
    const float* __restrict__ Qb, const float* __restrict__ Kb,
    const float* __restrict__ GK, const float* __restrict__ GQ,
    const float* __restrict__ Gxr, const float* __restrict__ Gxl,
    const float* __restrict__ xl, const float* __restrict__ xr,
    const int* __restrict__ dl, const int* __restrict__ dr,
    float* __restrict__ out)
{
    int blk = blockIdx.x;
    int wn = blk & 31; blk >>= 5;
    int hn = blk & 31; blk >>= 5;
    int b  = blk & 1;  blk >>= 1;
    int dir = blk;  // 0: out_left, 1: out_right

    const float* Amat = dir ? Kb : Qb;
    const float* Bg   = dir ? GQ : GK;
    const float* Xg   = dir ? Gxl : Gxr;
    const float* base = dir ? xr : xl;
    const int*  dd    = dir ? dr : dl;
    float* op = out + (size_t)dir * 8388608;

    __shared__ float A[64][65];
    __shared__ float Bm[64][65];
    __shared__ float S[64][65];
    __shared__ float rowsum[64];
    __shared__ float pmean[8];

    int tid = threadIdx.x;
    size_t abase = (size_t)b * 4194304 + (size_t)(hn * 8) * 256 + wn * 8;
    for (int i = tid; i < 4096; i += 256) {
        int cc = i >> 6, p1 = i & 63;
        A[p1][cc] = Amat[abase + (size_t)cc * 65536 + (p1 >> 3) * 256 + (p1 & 7)];
    }
    size_t gbase = (size_t)b * 4194304 + hn * 2048 + wn * 8;
    for (int i = tid; i < 4096; i += 256) {
        int cc = i >> 6, p2 = i & 63;
        Bm[p2][cc] = Bg[gbase + (size_t)cc * 65536 + (p2 >> 3) * 256 + (p2 & 7)];
    }
    __syncthreads();
    if (tid < 64) {
        float s = 0.f;
        #pragma unroll 8
        for (int cc = 0; cc < 64; ++cc) s += Bm[tid][cc];
        rowsum[tid] = s;
    }
    __syncthreads();
    if (tid < 8) {
        float s = 0.f;
        #pragma unroll
        for (int q = 0; q < 8; ++q) s += rowsum[tid * 8 + q];
        pmean[tid] = s * (1.f / 512.f);
    }
    __syncthreads();
    for (int i = tid; i < 4096; i += 256) {
        int p2 = i >> 6, cc = i & 63;
        Bm[p2][cc] -= pmean[p2 >> 3];
    }
    __syncthreads();

    int tp = (tid >> 4) << 2;
    int tc = (tid & 15) << 2;
    {   // S = A @ Bm^T
        float accs[4][4] = {};
        for (int cc = 0; cc < 64; ++cc) {
            float av[4], bv[4];
            #pragma unroll
            for (int i = 0; i < 4; ++i) av[i] = A[tp + i][cc];
            #pragma unroll
            for (int j = 0; j < 4; ++j) bv[j] = Bm[tc + j][cc];
            #pragma unroll
            for (int i = 0; i < 4; ++i)
                #pragma unroll
                for (int j = 0; j < 4; ++j)
                    accs[i][j] = fmaf(av[i], bv[j], accs[i][j]);
        }
        #pragma unroll
        for (int i = 0; i < 4; ++i)
            #pragma unroll
            for (int j = 0; j < 4; ++j)
                S[tp + i][tc + j] = accs[i][j];
    }
    __syncthreads();
    if (tid < 64) {
        float m = -3.0e38f;
        #pragma unroll 8
        for (int j = 0; j < 64; ++j) m = fmaxf(m, S[tid][j]);
        float ssum = 0.f;
        #pragma unroll 8
        for (int j = 0; j < 64; ++j) {
            float e = __expf(S[tid][j] - m);
            S[tid][j] = e; ssum += e;
        }
        float inv = 1.f / ssum;
        #pragma unroll 8
        for (int j = 0; j < 64; ++j) S[tid][j] *= inv;
    }
    __syncthreads();
    for (int i = tid; i < 4096; i += 256) {
        int cc = i >> 6, p2 = i & 63;
        Bm[p2][cc] = Xg[gbase + (size_t)cc * 65536 + (p2 >> 3) * 256 + (p2 & 7)];
    }
    __syncthreads();
    {   // out = S @ X, unpatchify, masked residual
        float accs[4][4] = {};
        for (int p2 = 0; p2 < 64; ++p2) {
            float sv[4], xv[4];
            #pragma unroll
            for (int i = 0; i < 4; ++i) sv[i] = S[tp + i][p2];
            #pragma unroll
            for (int j = 0; j < 4; ++j) xv[j] = Bm[p2][tc + j];
            #pragma unroll
            for (int i = 0; i < 4; ++i)
                #pragma unroll
                for (int j = 0; j < 4; ++j)
                    accs[i][j] = fmaf(sv[i], xv[j], accs[i][j]);
        }
        #pragma unroll
        for (int i = 0; i < 4; ++i) {
            int p1 = tp + i;
            int h1 = hn * 8 + (p1 >> 3), w1 = wn * 8 + (p1 & 7);
            int d = dd[(size_t)b * 65536 + h1 * 256 + w1];
            float msk = dir ? ((w1 + d <= 255) ? 1.f : 0.f)
                            : ((w1 - d >= 0) ? 1.f : 0.f);
            #pragma unroll
            for (int j = 0; j < 4; ++j) {
                int ch = tc + j;
                size_t o = (size_t)b * 4194304 + (size_t)ch * 65536 + (size_t)h1 * 256 + w1;
                op[o] = fmaf(accs[i][j], msk, base[o]);
            }
        }
    }
}

extern "C" void kernel_launch(void* const* d_in, const int* in_sizes, int n_in,
                              void* d_out, int out_size, void* d_ws, size_t ws_size,
                              hipStream_t stream) {
    (void)in_sizes; (void)n_in; (void)out_size; (void)ws_size;
    const float* x_left  = (const float*)d_in[0];
    const float* x_right = (const float*)d_in[1];
    const float* cat_l   = (const float*)d_in[2];
    const float* cat_r   = (const float*)d_in[3];
    const int*   d_left  = (const int*)d_in[4];
    const int*   d_right = (const int*)d_in[5];
    const float* gamma   = (const float*)d_in[6];
    const float* beta    = (const float*)d_in[7];
    const float* rb_w1   = (const float*)d_in[8];
    const float* rb_b1   = (const float*)d_in[9];
    const float* rb_w2   = (const float*)d_in[10];
    const float* rb_b2   = (const float*)d_in[11];
    const float* bq_w    = (const float*)d_in[12];
    const float* bq_b    = (const float*)d_in[13];
    const float* bs_w    = (const float*)d_in[14];
    const float* bs_b    = (const float*)d_in[15];
    float* out = (float*)d_out;
    float* ws  = (float*)d_ws;

    float* y1    = ws;               // 33,554,432 floats (reused per side)
    float* GK    = ws;               // alias after y1 is dead
    float* GQ    = ws + 8388608;
    float* Gxr   = ws + 16777216;
    float* Gxl   = ws + 25165824;
    float* Qb    = ws + 33554432;
    float* Kb    = ws + 41943040;
    float* stats = ws + 50331648;    // [2][scale 256 | shift 256]
    float* WfQ = Kb;                 // fold scratch in dead Kb region
    float* bfQ = Kb + 49152;
    float* WfK = out;                // d_out scratch until k_attn
    float* bfK = out + 49152;

    k_bnstats<<<512, 256, 0, stream>>>(cat_l, cat_r, gamma, beta, stats);
    k_fold<<<32, 256, 0, stream>>>(rb_w2, rb_b2, bq_w, bq_b, bs_w, bs_b, stats,
                                   WfQ, bfQ, WfK, bfK);
    k_conv1<<<2048, 256, 0, stream>>>(cat_l, stats, rb_w1, rb_b1, y1);
    k_conv2f<<<512, 256, 0, stream>>>(y1, cat_l, WfQ, bfQ, Qb);
    k_conv1<<<2048, 256, 0, stream>>>(cat_r, stats + 512, rb_w1, rb_b1, y1);
    k_conv2f<<<512, 256, 0, stream>>>(y1, cat_r, WfK, bfK, Kb);
    k_gather<<<2048, 256, 0, stream>>>(Kb, Qb, x_right, x_left, d_left, d_right,
                                       GK, GQ, Gxr, Gxl);
    k_attn<<<4096, 256, 0, stream>>>(Qb, Kb, GK, GQ, Gxr, Gxl,
                                     x_left, x_right, d_left, d_right, out);
}

// Round 8
// 2837.912 us; speedup vs baseline: 4.5101x; 4.5101x over previous
//
#include <hip/hip_runtime.h>

// ---------------------------------------------------------------------------
// PAM (parallax attention) forward, MI355X. Round 6:
// Round-5 structure VERIFIED CORRECT (absmax passed) but the compiler demoted
// the 2-D acc[4][16] to scratch under __launch_bounds__(256,3): VGPR=84,
// 9.4 GB scratch writes/dispatch, 3.4x regression. Fix: accumulators as four
// 1-D arrays (round-4's proven register-resident pattern) + plain
// __launch_bounds__(256). Structure otherwise identical:
//  - 32x32 tile, 4 adjacent rows/thread x 16 oc, overlapping 9-tap windows.
//  - single barrier per ic (double-buffer writes to the other buffer).
//  - conv2f: folded 1x1 (16 outputs) + cat residual.
//
// Workspace (floats) — unchanged:
//   [0, 33554432)        y1 ; later aliased GK@0, GQ@8388608, Gxr@16777216, Gxl@25165824
//   [33554432, 41943040) Q
//   [41943040, 50331648) K   (first 49216 floats used as WfQ/bfQ scratch pre-K)
//   [50331648, 50332672) bn stats: [side][scale(256), shift(256)]
// d_out used as scratch for WfK/bfK until k_attn writes it.
// ---------------------------------------------------------------------------

__global__ __launch_bounds__(256) void k_bnstats(
    const float* __restrict__ cat_l, const float* __restrict__ cat_r,
    const float* __restrict__ gamma, const float* __restrict__ beta,
    float* __restrict__ stats)
{
    int ch = blockIdx.x & 255;
    int side = blockIdx.x >> 8;
    const float* src = side ? cat_r : cat_l;
    int tid = threadIdx.x;
    float s = 0.f, s2 = 0.f;
    #pragma unroll
    for (int b = 0; b < 2; ++b) {
        const float* p = src + (size_t)b * 16777216 + (size_t)ch * 65536;
        for (int i = tid; i < 65536; i += 256) {
            float v = p[i];
            s += v; s2 += v * v;
        }
    }
    __shared__ float rs[256], rq[256];
    rs[tid] = s; rq[tid] = s2;
    __syncthreads();
    for (int off = 128; off > 0; off >>= 1) {
        if (tid < off) { rs[tid] += rs[tid + off]; rq[tid] += rq[tid + off]; }
        __syncthreads();
    }
    if (tid == 0) {
        float mean = rs[0] * (1.f / 131072.f);
        float var  = rq[0] * (1.f / 131072.f) - mean * mean;
        float rstd = rsqrtf(var + 1e-5f);
        float sc = gamma[ch] * rstd;
        stats[side * 512 + ch] = sc;
        stats[side * 512 + 256 + ch] = beta[ch] - mean * sc;
    }
}

// Fold grouped 1x1 (pw,pb) into conv2 3x3 weights + BN residual.
// Wf layout: [(g*64+ic)*16 + j] * 12 : [0..8]=Wtilde, [9]=pw[j][ic]*sc[ic], pad.
__global__ __launch_bounds__(256) void k_fold(
    const float* __restrict__ w2, const float* __restrict__ b2,
    const float* __restrict__ bqw, const float* __restrict__ bqb,
    const float* __restrict__ bsw, const float* __restrict__ bsb,
    const float* __restrict__ stats,
    float* __restrict__ WfQ, float* __restrict__ bfQ,
    float* __restrict__ WfK, float* __restrict__ bfK)
{
    int idx = blockIdx.x * 256 + threadIdx.x;
    int j    = idx & 15;
    int ic   = (idx >> 4) & 63;
    int g    = (idx >> 10) & 3;
    int side = (idx >> 12) & 1;
    const float* pw  = side ? bsw : bqw;
    const float* st  = stats + side * 512;
    const float* pwr = pw + (size_t)(g * 16 + j) * 64;
    const float* wbase = w2 + (size_t)(g * 64) * 576 + ic * 9;
    float a[9] = {0.f,0.f,0.f,0.f,0.f,0.f,0.f,0.f,0.f};
    #pragma unroll 4
    for (int oc = 0; oc < 64; ++oc) {
        float p = pwr[oc];
        const float* wrow = wbase + (size_t)oc * 576;
        #pragma unroll
        for (int k = 0; k < 9; ++k) a[k] = fmaf(p, wrow[k], a[k]);
    }
    float* dst = (side ? WfK : WfQ) + (size_t)((g * 64 + ic) * 16 + j) * 12;
    #pragma unroll
    for (int k = 0; k < 9; ++k) dst[k] = a[k];
    dst[9]  = pwr[ic] * st[g * 64 + ic];
    dst[10] = 0.f; dst[11] = 0.f;
    if (ic == 0) {
        float s = (side ? bsb : bqb)[g * 16 + j];
        for (int oc = 0; oc < 64; ++oc)
            s = fmaf(pwr[oc], b2[g * 64 + oc] + st[256 + g * 64 + oc], s);
        (side ? bfK : bfQ)[g * 16 + j] = s;
    }
}

// Grouped 3x3 conv (BN on the fly), bias + LeakyReLU(0.1).
// 32x32 tile, 4 adjacent rows/thread, 16 oc/block (oh quarter).
// Accumulators: four 1-D arrays (register-resident; 2-D form spilled).
__global__ __launch_bounds__(256) void k_conv1(
    const float* __restrict__ cat, const float* __restrict__ stats,
    const float* __restrict__ w1, const float* __restrict__ b1,
    float* __restrict__ y1)
{
    int blk = blockIdx.x;
    int wt = blk & 7;   blk >>= 3;
    int ht = blk & 7;   blk >>= 3;
    int oh = blk & 3;   blk >>= 2;
    int g  = blk & 3;   blk >>= 2;
    int b  = blk;
    int tid = threadIdx.x;
    int tw = tid & 31, th = tid >> 5;   // th 0..7
    int rb = th * 4;                    // local row base: rows rb..rb+3
    int h = ht * 32 + rb, w = wt * 32 + tw;

    __shared__ __align__(16) float tile[2][34][36];
    __shared__ __align__(16) float wb[2][16][12];

    float accA[16], accB[16], accC[16], accD[16];
    #pragma unroll
    for (int j = 0; j < 16; ++j) {
        float bb = b1[g * 64 + oh * 16 + j];
        accA[j] = bb; accB[j] = bb; accC[j] = bb; accD[j] = bb;
    }

    const float* catg = cat + ((size_t)b * 256 + g * 64) * 65536;
    const float* wg = w1 + (size_t)(g * 64 + oh * 16) * 576;
    int h0 = ht * 32 - 1, w0 = wt * 32 - 1;

    // staging geometry: 34x34 = 1156 elements, 5 slots/thread
    int soff[5]; int slds[5]; bool sin[5];
    #pragma unroll
    for (int s = 0; s < 5; ++s) {
        int idx = tid + 256 * s;
        int r = idx / 34, c = idx - r * 34;
        bool v = idx < 1156;
        int hh = h0 + r, ww = w0 + c;
        sin[s]  = v && (unsigned)hh < 256u && (unsigned)ww < 256u;
        soff[s] = hh * 256 + ww;
        slds[s] = v ? (r * 36 + c) : (33 * 36 + 35); // park OOB slots on a pad cell
    }
    // weight staging: 16 oc x 9 = 144, 1 slot/thread
    bool wvld = tid < 144;
    int woc = tid / 9, wk = tid - woc * 9;
    const float* wptr = wg + (size_t)woc * 576 + wk;
    int wlds = woc * 12 + wk;

    float t[5], wv, csn, shn;
    float* tile0 = &tile[0][0][0];
    float* wb0 = &wb[0][0][0];

    {   // prologue: stage ic=0 into buffer 0
        csn = stats[g * 64]; shn = stats[256 + g * 64];
        #pragma unroll
        for (int s = 0; s < 5; ++s) {
            t[s] = sin[s] ? catg[soff[s]] : 0.f;
            tile0[slds[s]] = sin[s] ? fmaf(t[s], csn, shn) : 0.f;
        }
        if (wvld) wb0[wlds] = wptr[0];
    }
    __syncthreads();

    int cur = 0;
    for (int ic = 0; ic < 64; ++ic) {
        bool pf = (ic + 1 < 64);
        if (pf) {   // issue next-ic loads early
            const float* plane = catg + (size_t)(ic + 1) * 65536;
            csn = stats[g * 64 + ic + 1];
            shn = stats[256 + g * 64 + ic + 1];
            #pragma unroll
            for (int s = 0; s < 5; ++s) t[s] = sin[s] ? plane[soff[s]] : 0.f;
            wv = wvld ? wptr[(ic + 1) * 9] : 0.f;
        }
        float xr[6][3];
        #pragma unroll
        for (int rr = 0; rr < 6; ++rr)
            #pragma unroll
            for (int cc = 0; cc < 3; ++cc)
                xr[rr][cc] = tile[cur][rb + rr][tw + cc];
        #pragma unroll
        for (int j = 0; j < 16; ++j) {
            float4 wa = *(const float4*)&wb[cur][j][0];
            float4 wc = *(const float4*)&wb[cur][j][4];
            float w8  = wb[cur][j][8];
            float s0 = accA[j], s1 = accB[j], s2 = accC[j], s3 = accD[j];
            s0 = fmaf(wa.x, xr[0][0], s0); s1 = fmaf(wa.x, xr[1][0], s1);
            s2 = fmaf(wa.x, xr[2][0], s2); s3 = fmaf(wa.x, xr[3][0], s3);
            s0 = fmaf(wa.y, xr[0][1], s0); s1 = fmaf(wa.y, xr[1][1], s1);
            s2 = fmaf(wa.y, xr[2][1], s2); s3 = fmaf(wa.y, xr[3][1], s3);
            s0 = fmaf(wa.z, xr[0][2], s0); s1 = fmaf(wa.z, xr[1][2], s1);
            s2 = fmaf(wa.z, xr[2][2], s2); s3 = fmaf(wa.z, xr[3][2], s3);
            s0 = fmaf(wa.w, xr[1][0], s0); s1 = fmaf(wa.w, xr[2][0], s1);
            s2 = fmaf(wa.w, xr[3][0], s2); s3 = fmaf(wa.w, xr[4][0], s3);
            s0 = fmaf(wc.x, xr[1][1], s0); s1 = fmaf(wc.x, xr[2][1], s1);
            s2 = fmaf(wc.x, xr[3][1], s2); s3 = fmaf(wc.x, xr[4][1], s3);
            s0 = fmaf(wc.y, xr[1][2], s0); s1 = fmaf(wc.y, xr[2][2], s1);
            s2 = fmaf(wc.y, xr[3][2], s2); s3 = fmaf(wc.y, xr[4][2], s3);
            s0 = fmaf(wc.z, xr[2][0], s0); s1 = fmaf(wc.z, xr[3][0], s1);
            s2 = fmaf(wc.z, xr[4][0], s2); s3 = fmaf(wc.z, xr[5][0], s3);
            s0 = fmaf(wc.w, xr[2][1], s0); s1 = fmaf(wc.w, xr[3][1], s1);
            s2 = fmaf(wc.w, xr[4][1], s2); s3 = fmaf(wc.w, xr[5][1], s3);
            s0 = fmaf(w8,   xr[2][2], s0); s1 = fmaf(w8,   xr[3][2], s1);
            s2 = fmaf(w8,   xr[4][2], s2); s3 = fmaf(w8,   xr[5][2], s3);
            accA[j] = s0; accB[j] = s1; accC[j] = s2; accD[j] = s3;
        }
        if (pf) {   // write OTHER buffer: no barrier needed before writes
            float* tn = &tile[cur ^ 1][0][0];
            #pragma unroll
            for (int s = 0; s < 5; ++s)
                tn[slds[s]] = sin[s] ? fmaf(t[s], csn, shn) : 0.f;
            if (wvld) (&wb[cur ^ 1][0][0])[wlds] = wv;
        }
        __syncthreads();   // single barrier: orders RAW (nb) and WAR (cur)
        cur ^= 1;
    }

    float* yp = y1 + ((size_t)b * 256 + g * 64 + oh * 16) * 65536
                   + (size_t)h * 256 + w;
    #pragma unroll
    for (int j = 0; j < 16; ++j) {
        float v0 = accA[j], v1 = accB[j], v2 = accC[j], v3 = accD[j];
        yp[(size_t)j * 65536 +   0] = v0 > 0.f ? v0 : 0.1f * v0;
        yp[(size_t)j * 65536 + 256] = v1 > 0.f ? v1 : 0.1f * v1;
        yp[(size_t)j * 65536 + 512] = v2 > 0.f ? v2 : 0.1f * v2;
        yp[(size_t)j * 65536 + 768] = v3 > 0.f ? v3 : 0.1f * v3;
    }
}

// Folded conv2: 16 outputs per group (Wtilde 3x3 over y1 + pwsc*cat residual).
// Same 32x32 / 4-row / single-barrier structure; 1-D accumulator arrays.
__global__ __launch_bounds__(256) void k_conv2f(
    const float* __restrict__ y1, const float* __restrict__ cat,
    const float* __restrict__ Wf, const float* __restrict__ bf,
    float* __restrict__ Qout)
{
    int blk = blockIdx.x;
    int wt = blk & 7;   blk >>= 3;
    int ht = blk & 7;   blk >>= 3;
    int g  = blk & 3;   blk >>= 2;
    int b  = blk;
    int tid = threadIdx.x;
    int tw = tid & 31, th = tid >> 5;
    int rb = th * 4;
    int h = ht * 32 + rb, w = wt * 32 + tw;

    __shared__ __align__(16) float tile[2][34][36];
    __shared__ __align__(16) float wb[2][16][12];

    float accA[16], accB[16], accC[16], accD[16];
    #pragma unroll
    for (int j = 0; j < 16; ++j) {
        float bb = bf[g * 16 + j];
        accA[j] = bb; accB[j] = bb; accC[j] = bb; accD[j] = bb;
    }

    const float* yg = y1 + ((size_t)b * 256 + g * 64) * 65536;
    const float* catp = cat + ((size_t)b * 256 + g * 64) * 65536
                            + (size_t)h * 256 + w;
    const float* wfg = Wf + (size_t)(g * 64) * 192;
    int h0 = ht * 32 - 1, w0 = wt * 32 - 1;

    int soff[5]; int slds[5]; bool sin[5];
    #pragma unroll
    for (int s = 0; s < 5; ++s) {
        int idx = tid + 256 * s;
        int r = idx / 34, c = idx - r * 34;
        bool v = idx < 1156;
        int hh = h0 + r, ww = w0 + c;
        sin[s]  = v && (unsigned)hh < 256u && (unsigned)ww < 256u;
        soff[s] = hh * 256 + ww;
        slds[s] = v ? (r * 36 + c) : (33 * 36 + 35);
    }
    bool wvld = tid < 192;   // 16 j x 12
    float t[5], wv, cv0, cv1, cv2, cv3, ncv0, ncv1, ncv2, ncv3;
    float* tile0 = &tile[0][0][0];

    {   // prologue ic=0
        #pragma unroll
        for (int s = 0; s < 5; ++s) {
            t[s] = sin[s] ? yg[soff[s]] : 0.f;
            tile0[slds[s]] = t[s];
        }
        if (wvld) (&wb[0][0][0])[tid] = wfg[tid];
        cv0 = catp[0]; cv1 = catp[256]; cv2 = catp[512]; cv3 = catp[768];
    }
    __syncthreads();

    int cur = 0;
    for (int ic = 0; ic < 64; ++ic) {
        bool pf = (ic + 1 < 64);
        if (pf) {
            const float* plane = yg + (size_t)(ic + 1) * 65536;
            #pragma unroll
            for (int s = 0; s < 5; ++s) t[s] = sin[s] ? plane[soff[s]] : 0.f;
            wv = wvld ? wfg[(size_t)(ic + 1) * 192 + tid] : 0.f;
            const float* cp = catp + (size_t)(ic + 1) * 65536;
            ncv0 = cp[0]; ncv1 = cp[256]; ncv2 = cp[512]; ncv3 = cp[768];
        }
        float xr[6][3];
        #pragma unroll
        for (int rr = 0; rr < 6; ++rr)
            #pragma unroll
            for (int cc = 0; cc < 3; ++cc)
                xr[rr][cc] = tile[cur][rb + rr][tw + cc];
        #pragma unroll
        for (int j = 0; j < 16; ++j) {
            float4 wa = *(const float4*)&wb[cur][j][0];
            float4 wc = *(const float4*)&wb[cur][j][4];
            float4 wd = *(const float4*)&wb[cur][j][8];  // x=w8, y=pws
            float s0 = accA[j], s1 = accB[j], s2 = accC[j], s3 = accD[j];
            s0 = fmaf(wa.x, xr[0][0], s0); s1 = fmaf(wa.x, xr[1][0], s1);
            s2 = fmaf(wa.x, xr[2][0], s2); s3 = fmaf(wa.x, xr[3][0], s3);
            s0 = fmaf(wa.y, xr[0][1], s0); s1 = fmaf(wa.y, xr[1][1], s1);
            s2 = fmaf(wa.y, xr[2][1], s2); s3 = fmaf(wa.y, xr[3][1], s3);
            s0 = fmaf(wa.z, xr[0][2], s0); s1 = fmaf(wa.z, xr[1][2], s1);
            s2 = fmaf(wa.z, xr[2][2], s2); s3 = fmaf(wa.z, xr[3][2], s3);
            s0 = fmaf(wa.w, xr[1][0], s0); s1 = fmaf(wa.w, xr[2][0], s1);
            s2 = fmaf(wa.w, xr[3][0], s2); s3 = fmaf(wa.w, xr[4][0], s3);
            s0 = fmaf(wc.x, xr[1][1], s0); s1 = fmaf(wc.x, xr[2][1], s1);
            s2 = fmaf(wc.x, xr[3][1], s2); s3 = fmaf(wc.x, xr[4][1], s3);
            s0 = fmaf(wc.y, xr[1][2], s0); s1 = fmaf(wc.y, xr[2][2], s1);
            s2 = fmaf(wc.y, xr[3][2], s2); s3 = fmaf(wc.y, xr[4][2], s3);
            s0 = fmaf(wc.z, xr[2][0], s0); s1 = fmaf(wc.z, xr[3][0], s1);
            s2 = fmaf(wc.z, xr[4][0], s2); s3 = fmaf(wc.z, xr[5][0], s3);
            s0 = fmaf(wc.w, xr[2][1], s0); s1 = fmaf(wc.w, xr[3][1], s1);
            s2 = fmaf(wc.w, xr[4][1], s2); s3 = fmaf(wc.w, xr[5][1], s3);
            s0 = fmaf(wd.x, xr[2][2], s0); s1 = fmaf(wd.x, xr[3][2], s1);
            s2 = fmaf(wd.x, xr[4][2], s2); s3 = fmaf(wd.x, xr[5][2], s3);
            s0 = fmaf(wd.y, cv0, s0);      s1 = fmaf(wd.y, cv1, s1);
            s2 = fmaf(wd.y, cv2, s2);      s3 = fmaf(wd.y, cv3, s3);
            accA[j] = s0; accB[j] = s1; accC[j] = s2; accD[j] = s3;
        }
        if (pf) {
            float* tn = &tile[cur ^ 1][0][0];
            #pragma unroll
            for (int s = 0; s < 5; ++s) tn[slds[s]] = t[s];
            if (wvld) (&wb[cur ^ 1][0][0])[tid] = wv;
            cv0 = ncv0; cv1 = ncv1; cv2 = ncv2; cv3 = ncv3;
        }
        __syncthreads();
        cur ^= 1;
    }

    float* qp = Qout + ((size_t)b * 64 + g * 16) * 65536 + (size_t)h * 256 + w;
    #pragma unroll
    for (int j = 0; j < 16; ++j) {
        qp[(size_t)j * 65536 +   0] = accA[j];
        qp[(size_t)j * 65536 + 256] = accB[j];
        qp[(size_t)j * 65536 + 512] = accC[j];
        qp[(size_t)j * 65536 + 768] = accD[j];
    }
}

// Horizontal disparity gathers, output in [b,h,w,c] layout (flat-index ready).
__global__ __launch_bounds__(256) void k_gather(
    const float* __restrict__ Kb, const float* __restrict__ Qb,
    const float* __restrict__ xr, const float* __restrict__ xl,
    const int* __restrict__ dl, const int* __restrict__ dr,
    float* __restrict__ GK, float* __restrict__ GQ,
    float* __restrict__ Gxr, float* __restrict__ Gxl)
{
    int blk = blockIdx.x;
    int h = blk & 255; blk >>= 8;
    int b = blk & 1;   blk >>= 1;
    int sel = blk;
    const float* src; float* dst; const int* dd; int r2l;
    if (sel == 0)      { src = Kb; dst = GK;  dd = dl; r2l = 1; }
    else if (sel == 1) { src = Qb; dst = GQ;  dd = dr; r2l = 0; }
    else if (sel == 2) { src = xr; dst = Gxr; dd = dl; r2l = 1; }
    else               { src = xl; dst = Gxl; dd = dr; r2l = 0; }
    const int* drow = dd + ((size_t)b * 256 + h) * 256;
    const float* sp = src + (size_t)b * 4194304 + h * 256;
    float* dp = dst + ((size_t)b * 256 + h) * 16384;
    int tid = threadIdx.x;
    for (int i = tid; i < 16384; i += 256) {
        int w = i >> 6, cc = i & 63;
        int d = drow[w];
        int wi = r2l ? (w - d < 0 ? 0 : w - d) : (w + d > 255 ? 255 : w + d);
        dp[i] = sp[(size_t)cc * 65536 + wi];
    }
}

// Per-window attention: score = patchA @ centered(sel)^T, softmax, @ x_sel,
// unpatchify + masked residual. One block per (dir, b, hn, wn).
__global__ __launch_bounds__(256) void k_attn(
    const float* __restrict__ Qb, const float* __restrict__ Kb,
    const float* __restrict__ GK, const float* __restrict__ GQ,
    const float* __restrict__ Gxr, const float* __restrict__ Gxl,
    const float* __restrict__ xl, const float* __restrict__ xr,
    const int* __restrict__ dl, const int* __restrict__ dr,
    float* __restrict__ out)
{
    int blk = blockIdx.x;
    int wn = blk & 31; blk >>= 5;
    int hn = blk & 31; blk >>= 5;
    int b  = blk & 1;  blk >>= 1;
    int dir = blk;  // 0: out_left, 1: out_right

    const float* Amat = dir ? Kb : Qb;
    const float* Bg   = dir ? GQ : GK;
    const float* Xg   = dir ? Gxl : Gxr;
    const float* base = dir ? xr : xl;
    const int*  dd    = dir ? dr : dl;
    float* op = out + (size_t)dir * 8388608;

    __shared__ float A[64][65];
    __shared__ float Bm[64][65];
    __shared__ float S[64][65];
    __shared__ float rowsum[64];
    __shared__ float pmean[8];

    int tid = threadIdx.x;
    size_t abase = (size_t)b * 4194304 + (size_t)(hn * 8) * 256 + wn * 8;
    for (int i = tid; i < 4096; i += 256) {
        int cc = i >> 6, p1 = i & 63;
        A[p1][cc] = Amat[abase + (size_t)cc * 65536 + (p1 >> 3) * 256 + (p1 & 7)];
    }
    size_t gbase = (size_t)b * 4194304 + hn * 2048 + wn * 8;
    for (int i = tid; i < 4096; i += 256) {
        int cc = i >> 6, p2 = i & 63;
        Bm[p2][cc] = Bg[gbase + (size_t)cc * 65536 + (p2 >> 3) * 256 + (p2 & 7)];
    }
    __syncthreads();
    if (tid < 64) {
        float s = 0.f;
        #pragma unroll 8
        for (int cc = 0; cc < 64; ++cc) s += Bm[tid][cc];
        rowsum[tid] = s;
    }
    __syncthreads();
    if (tid < 8) {
        float s = 0.f;
        #pragma unroll
        for (int q = 0; q < 8; ++q) s += rowsum[tid * 8 + q];
        pmean[tid] = s * (1.f / 512.f);
    }
    __syncthreads();
    for (int i = tid; i < 4096; i += 256) {
        int p2 = i >> 6, cc = i & 63;
        Bm[p2][cc] -= pmean[p2 >> 3];
    }
    __syncthreads();

    int tp = (tid >> 4) << 2;
    int tc = (tid & 15) << 2;
    {   // S = A @ Bm^T
        float accs[4][4] = {};
        for (int cc = 0; cc < 64; ++cc) {
            float av[4], bv[4];
            #pragma unroll
            for (int i = 0; i < 4; ++i) av[i] = A[tp + i][cc];
            #pragma unroll
            for (int j = 0; j < 4; ++j) bv[j] = Bm[tc + j][cc];
            #pragma unroll
            for (int i = 0; i < 4; ++i)
                #pragma unroll
                for (int j = 0; j < 4; ++j)
                    accs[i][j] = fmaf(av[i], bv[j], accs[i][j]);
        }
        #pragma unroll
        for (int i = 0; i < 4; ++i)
            #pragma unroll
            for (int j = 0; j < 4; ++j)
                S[tp + i][tc + j] = accs[i][j];
    }
    __syncthreads();
    if (tid < 64) {
        float m = -3.0e38f;
        #pragma unroll 8
        for (int j = 0; j < 64; ++j) m = fmaxf(m, S[tid][j]);
        float ssum = 0.f;
        #pragma unroll 8
        for (int j = 0; j < 64; ++j) {
            float e = __expf(S[tid][j] - m);
            S[tid][j] = e; ssum += e;
        }
        float inv = 1.f / ssum;
        #pragma unroll 8
        for (int j = 0; j < 64; ++j) S[tid][j] *= inv;
    }
    __syncthreads();
    for (int i = tid; i < 4096; i += 256) {
        int cc = i >> 6, p2 = i & 63;
        Bm[p2][cc] = Xg[gbase + (size_t)cc * 65536 + (p2 >> 3) * 256 + (p2 & 7)];
    }
    __syncthreads();
    {   // out = S @ X, unpatchify, masked residual
        float accs[4][4] = {};
        for (int p2 = 0; p2 < 64; ++p2) {
            float sv[4], xv[4];
            #pragma unroll
            for (int i = 0; i < 4; ++i) sv[i] = S[tp + i][p2];
            #pragma unroll
            for (int j = 0; j < 4; ++j) xv[j] = Bm[p2][tc + j];
            #pragma unroll
            for (int i = 0; i < 4; ++i)
                #pragma unroll
                for (int j = 0; j < 4; ++j)
                    accs[i][j] = fmaf(sv[i], xv[j], accs[i][j]);
        }
        #pragma unroll
        for (int i = 0; i < 4; ++i) {
            int p1 = tp + i;
            int h1 = hn * 8 + (p1 >> 3), w1 = wn * 8 + (p1 & 7);
            int d = dd[(size_t)b * 65536 + h1 * 256 + w1];
            float msk = dir ? ((w1 + d <= 255) ? 1.f : 0.f)
                            : ((w1 - d >= 0) ? 1.f : 0.f);
            #pragma unroll
            for (int j = 0; j < 4; ++j) {
                int ch = tc + j;
                size_t o = (size_t)b * 4194304 + (size_t)ch * 65536 + (size_t)h1 * 256 + w1;
                op[o] = fmaf(accs[i][j], msk, base[o]);
            }
        }
    }
}

extern "C" void kernel_launch(void* const* d_in, const int* in_sizes, int n_in,
                              void* d_out, int out_size, void* d_ws, size_t ws_size,
                              hipStream_t stream) {
    (void)in_sizes; (void)n_in; (void)out_size; (void)ws_size;
    const float* x_left  = (const float*)d_in[0];
    const float* x_right = (const float*)d_in[1];
    const float* cat_l   = (const float*)d_in[2];
    const float* cat_r   = (const float*)d_in[3];
    const int*   d_left  = (const int*)d_in[4];
    const int*   d_right = (const int*)d_in[5];
    const float* gamma   = (const float*)d_in[6];
    const float* beta    = (const float*)d_in[7];
    const float* rb_w1   = (const float*)d_in[8];
    const float* rb_b1   = (const float*)d_in[9];
    const float* rb_w2   = (const float*)d_in[10];
    const float* rb_b2   = (const float*)d_in[11];
    const float* bq_w    = (const float*)d_in[12];
    const float* bq_b    = (const float*)d_in[13];
    const float* bs_w    = (const float*)d_in[14];
    const float* bs_b    = (const float*)d_in[15];
    float* out = (float*)d_out;
    float* ws  = (float*)d_ws;

    float* y1    = ws;               // 33,554,432 floats (reused per side)
    float* GK    = ws;               // alias after y1 is dead
    float* GQ    = ws + 8388608;
    float* Gxr   = ws + 16777216;
    float* Gxl   = ws + 25165824;
    float* Qb    = ws + 33554432;
    float* Kb    = ws + 41943040;
    float* stats = ws + 50331648;    // [2][scale 256 | shift 256]
    float* WfQ = Kb;                 // fold scratch in dead Kb region
    float* bfQ = Kb + 49152;
    float* WfK = out;                // d_out scratch until k_attn
    float* bfK = out + 49152;

    k_bnstats<<<512, 256, 0, stream>>>(cat_l, cat_r, gamma, beta, stats);
    k_fold<<<32, 256, 0, stream>>>(rb_w2, rb_b2, bq_w, bq_b, bs_w, bs_b, stats,
                                   WfQ, bfQ, WfK, bfK);
    k_conv1<<<2048, 256, 0, stream>>>(cat_l, stats, rb_w1, rb_b1, y1);
    k_conv2f<<<512, 256, 0, stream>>>(y1, cat_l, WfQ, bfQ, Qb);
    k_conv1<<<2048, 256, 0, stream>>>(cat_r, stats + 512, rb_w1, rb_b1, y1);
    k_conv2f<<<512, 256, 0, stream>>>(y1, cat_r, WfK, bfK, Kb);
    k_gather<<<2048, 256, 0, stream>>>(Kb, Qb, x_right, x_left, d_left, d_right,
                                       GK, GQ, Gxr, Gxl);
    k_attn<<<4096, 256, 0, stream>>>(Qb, Kb, GK, GQ, Gxr, Gxl,
                                     x_left, x_right, d_left, d_right, out);
}

// Round 13
// 2366.357 us; speedup vs baseline: 5.4088x; 1.1993x over previous
//
#include <hip/hip_runtime.h>

// ---------------------------------------------------------------------------
// PAM (parallax attention) forward, MI355X. Round 7 (fifth submit — rounds
// 9-12 were GPU-broker infra failures; this kernel has never been measured):
// Round-6 counters: k_conv1 817us, VALUBusy 44% — LDS-pipe-bound. Per ic/wave:
// FMA 1152 cyc (per-SIMD) vs LDS 584 cyc (per-CU pipe, 8 waves -> 4672 cyc);
// 80% of LDS = redundant weight broadcasts (every wave reads all 16 oc).
// Fix: wave->oc specialization in k_conv1. Each wave owns 4 oc, covers the
// whole 32x32 tile at 4x4 px/thread (lane -> 8x8 (rg,cg) grid):
//   - weight LDS reads/wave/ic: 480 -> 120 cyc (4x)
//   - xv reads: contiguous 6-col spans -> b128+b64 (12 instr/ic)
//   - epilogue: float4 stores
// conv2f unchanged this round (port next if verified).
//
// Workspace (floats) — unchanged:
//   [0, 33554432)        y1 ; later aliased GK@0, GQ@8388608, Gxr@16777216, Gxl@25165824
//   [33554432, 41943040) Q
//   [41943040, 50331648) K   (first 49216 floats used as WfQ/bfQ scratch pre-K)
//   [50331648, 50332672) bn stats: [side][scale(256), shift(256)]
// d_out used as scratch for WfK/bfK until k_attn writes it.
// ---------------------------------------------------------------------------

__global__ __launch_bounds__(256) void k_bnstats(
    const float* __restrict__ cat_l, const float* __restrict__ cat_r,
    const float* __restrict__ gamma, const float* __restrict__ beta,
    float* __restrict__ stats)
{
    int ch = blockIdx.x & 255;
    int side = blockIdx.x >> 8;
    const float* src = side ? cat_r : cat_l;
    int tid = threadIdx.x;
    float s = 0.f, s2 = 0.f;
    #pragma unroll
    for (int b = 0; b < 2; ++b) {
        const float* p = src + (size_t)b * 16777216 + (size_t)ch * 65536;
        for (int i = tid; i < 65536; i += 256) {
            float v = p[i];
            s += v; s2 += v * v;
        }
    }
    __shared__ float rs[256], rq[256];
    rs[tid] = s; rq[tid] = s2;
    __syncthreads();
    for (int off = 128; off > 0; off >>= 1) {
        if (tid < off) { rs[tid] += rs[tid + off]; rq[tid] += rq[tid + off]; }
        __syncthreads();
    }
    if (tid == 0) {
        float mean = rs[0] * (1.f / 131072.f);
        float var  = rq[0] * (1.f / 131072.f) - mean * mean;
        float rstd = rsqrtf(var + 1e-5f);
        float sc = gamma[ch] * rstd;
        stats[side * 512 + ch] = sc;
        stats[side * 512 + 256 + ch] = beta[ch] - mean * sc;
    }
}

// Fold grouped 1x1 (pw,pb) into conv2 3x3 weights + BN residual.
// Wf layout: [(g*64+ic)*16 + j] * 12 : [0..8]=Wtilde, [9]=pw[j][ic]*sc[ic], pad.
__global__ __launch_bounds__(256) void k_fold(
    const float* __restrict__ w2, const float* __restrict__ b2,
    const float* __restrict__ bqw, const float* __restrict__ bqb,
    const float* __restrict__ bsw, const float* __restrict__ bsb,
    const float* __restrict__ stats,
    float* __restrict__ WfQ, float* __restrict__ bfQ,
    float* __restrict__ WfK, float* __restrict__ bfK)
{
    int idx = blockIdx.x * 256 + threadIdx.x;
    int j    = idx & 15;
    int ic   = (idx >> 4) & 63;
    int g    = (idx >> 10) & 3;
    int side = (idx >> 12) & 1;
    const float* pw  = side ? bsw : bqw;
    const float* st  = stats + side * 512;
    const float* pwr = pw + (size_t)(g * 16 + j) * 64;
    const float* wbase = w2 + (size_t)(g * 64) * 576 + ic * 9;
    float a[9] = {0.f,0.f,0.f,0.f,0.f,0.f,0.f,0.f,0.f};
    #pragma unroll 4
    for (int oc = 0; oc < 64; ++oc) {
        float p = pwr[oc];
        const float* wrow = wbase + (size_t)oc * 576;
        #pragma unroll
        for (int k = 0; k < 9; ++k) a[k] = fmaf(p, wrow[k], a[k]);
    }
    float* dst = (side ? WfK : WfQ) + (size_t)((g * 64 + ic) * 16 + j) * 12;
    #pragma unroll
    for (int k = 0; k < 9; ++k) dst[k] = a[k];
    dst[9]  = pwr[ic] * st[g * 64 + ic];
    dst[10] = 0.f; dst[11] = 0.f;
    if (ic == 0) {
        float s = (side ? bsb : bqb)[g * 16 + j];
        for (int oc = 0; oc < 64; ++oc)
            s = fmaf(pwr[oc], b2[g * 64 + oc] + st[256 + g * 64 + oc], s);
        (side ? bfK : bfQ)[g * 16 + j] = s;
    }
}

// Grouped 3x3 conv (BN on the fly), bias + LeakyReLU(0.1).
// 32x32 tile; wave w owns oc oh*16+w*4..+3; each thread computes a 4x4 px
// block (lane -> rg=lane>>3, cg=lane&7). Four 1-D register accumulators.
__global__ __launch_bounds__(256) void k_conv1(
    const float* __restrict__ cat, const float* __restrict__ stats,
    const float* __restrict__ w1, const float* __restrict__ b1,
    float* __restrict__ y1)
{
    int blk = blockIdx.x;
    int wt = blk & 7;   blk >>= 3;
    int ht = blk & 7;   blk >>= 3;
    int oh = blk & 3;   blk >>= 2;
    int g  = blk & 3;   blk >>= 2;
    int b  = blk;
    int tid = threadIdx.x;
    int wid = tid >> 6;            // wave 0..3 -> oc base oh*16 + wid*4
    int lane = tid & 63;
    int rg = lane >> 3, cg = lane & 7;
    int r4 = rg * 4, c4 = cg * 4;

    __shared__ __align__(16) float tile[2][34][36];
    __shared__ __align__(16) float wb[2][16][12];

    float accA[16], accB[16], accC[16], accD[16];
    {
        int ob = g * 64 + oh * 16 + wid * 4;
        float b0 = b1[ob], b1v = b1[ob + 1], b2v = b1[ob + 2], b3v = b1[ob + 3];
        #pragma unroll
        for (int p = 0; p < 16; ++p) {
            accA[p] = b0; accB[p] = b1v; accC[p] = b2v; accD[p] = b3v;
        }
    }

    const float* catg = cat + ((size_t)b * 256 + g * 64) * 65536;
    const float* wg = w1 + (size_t)(g * 64 + oh * 16) * 576;
    int h0 = ht * 32 - 1, w0 = wt * 32 - 1;

    // staging geometry: 34x34 = 1156 elements, 5 slots/thread
    int soff[5]; int slds[5]; bool sin[5];
    #pragma unroll
    for (int s = 0; s < 5; ++s) {
        int idx = tid + 256 * s;
        int r = idx / 34, c = idx - r * 34;
        bool v = idx < 1156;
        int hh = h0 + r, ww = w0 + c;
        sin[s]  = v && (unsigned)hh < 256u && (unsigned)ww < 256u;
        soff[s] = hh * 256 + ww;
        slds[s] = v ? (r * 36 + c) : (33 * 36 + 35); // park OOB on a pad cell
    }
    // weight staging: 16 oc x 9 = 144, 1 slot/thread
    bool wvld = tid < 144;
    int woc = tid / 9, wk = tid - woc * 9;
    const float* wptr = wg + (size_t)woc * 576 + wk;
    int wlds = woc * 12 + wk;

    float t[5], wv, csn, shn;
    float* tile0 = &tile[0][0][0];
    float* wb0 = &wb[0][0][0];

    {   // prologue: stage ic=0 into buffer 0
        csn = stats[g * 64]; shn = stats[256 + g * 64];
        #pragma unroll
        for (int s = 0; s < 5; ++s) {
            t[s] = sin[s] ? catg[soff[s]] : 0.f;
            tile0[slds[s]] = sin[s] ? fmaf(t[s], csn, shn) : 0.f;
        }
        if (wvld) wb0[wlds] = wptr[0];
    }
    __syncthreads();

    int cur = 0;
    for (int ic = 0; ic < 64; ++ic) {
        bool pf = (ic + 1 < 64);
        if (pf) {   // issue next-ic loads early
            const float* plane = catg + (size_t)(ic + 1) * 65536;
            csn = stats[g * 64 + ic + 1];
            shn = stats[256 + g * 64 + ic + 1];
            #pragma unroll
            for (int s = 0; s < 5; ++s) t[s] = sin[s] ? plane[soff[s]] : 0.f;
            wv = wvld ? wptr[(ic + 1) * 9] : 0.f;
        }
        // 6x6 input patch, vector LDS reads (b128 + b64 per row)
        float xr[6][6];
        #pragma unroll
        for (int r2 = 0; r2 < 6; ++r2) {
            const float* rp = &tile[cur][r4 + r2][c4];
            float4 v4 = *(const float4*)rp;
            float2 v2 = *(const float2*)(rp + 4);
            xr[r2][0] = v4.x; xr[r2][1] = v4.y; xr[r2][2] = v4.z;
            xr[r2][3] = v4.w; xr[r2][4] = v2.x; xr[r2][5] = v2.y;
        }
        #define DO_OC(ACC, JO)                                              \
        {                                                                   \
            float4 wa = *(const float4*)&wb[cur][wid * 4 + JO][0];          \
            float4 wc = *(const float4*)&wb[cur][wid * 4 + JO][4];          \
            float w8  = wb[cur][wid * 4 + JO][8];                           \
            _Pragma("unroll")                                               \
            for (int rr = 0; rr < 4; ++rr) {                                \
                _Pragma("unroll")                                           \
                for (int cc = 0; cc < 4; ++cc) {                            \
                    float s = ACC[rr * 4 + cc];                             \
                    s = fmaf(wa.x, xr[rr    ][cc    ], s);                  \
                    s = fmaf(wa.y, xr[rr    ][cc + 1], s);                  \
                    s = fmaf(wa.z, xr[rr    ][cc + 2], s);                  \
                    s = fmaf(wa.w, xr[rr + 1][cc    ], s);                  \
                    s = fmaf(wc.x, xr[rr + 1][cc + 1], s);                  \
                    s = fmaf(wc.y, xr[rr + 1][cc + 2], s);                  \
                    s = fmaf(wc.z, xr[rr + 2][cc    ], s);                  \
                    s = fmaf(wc.w, xr[rr + 2][cc + 1], s);                  \
                    s = fmaf(w8,   xr[rr + 2][cc + 2], s);                  \
                    ACC[rr * 4 + cc] = s;                                   \
                }                                                           \
            }                                                               \
        }
        DO_OC(accA, 0)
        DO_OC(accB, 1)
        DO_OC(accC, 2)
        DO_OC(accD, 3)
        #undef DO_OC
        if (pf) {   // write OTHER buffer: no barrier needed before writes
            float* tn = &tile[cur ^ 1][0][0];
            #pragma unroll
            for (int s = 0; s < 5; ++s)
                tn[slds[s]] = sin[s] ? fmaf(t[s], csn, shn) : 0.f;
            if (wvld) (&wb[cur ^ 1][0][0])[wlds] = wv;
        }
        __syncthreads();   // single barrier: orders RAW (nb) and WAR (cur)
        cur ^= 1;
    }

    // epilogue: leaky-relu, float4 stores (4 rows x 4 oc per thread)
    float* yp = y1 + ((size_t)b * 256 + g * 64 + oh * 16 + wid * 4) * 65536
              + (size_t)(ht * 32 + r4) * 256 + wt * 32 + c4;
    #define STORE_OC(ACC, JO)                                               \
    {                                                                       \
        float* op = yp + (size_t)(JO) * 65536;                              \
        _Pragma("unroll")                                                   \
        for (int rr = 0; rr < 4; ++rr) {                                    \
            float v0 = ACC[rr * 4 + 0], v1 = ACC[rr * 4 + 1];               \
            float v2 = ACC[rr * 4 + 2], v3 = ACC[rr * 4 + 3];               \
            float4 o;                                                       \
            o.x = v0 > 0.f ? v0 : 0.1f * v0;                                \
            o.y = v1 > 0.f ? v1 : 0.1f * v1;                                \
            o.z = v2 > 0.f ? v2 : 0.1f * v2;                                \
            o.w = v3 > 0.f ? v3 : 0.1f * v3;                                \
            *(float4*)(op + rr * 256) = o;                                  \
        }                                                                   \
    }
    STORE_OC(accA, 0)
    STORE_OC(accB, 1)
    STORE_OC(accC, 2)
    STORE_OC(accD, 3)
    #undef STORE_OC
}

// Folded conv2: 16 outputs per group (Wtilde 3x3 over y1 + pwsc*cat residual).
// 32x32 / 4-row / single-barrier structure; 1-D accumulator arrays.
// (unchanged from round 6; port wave-oc split next round if conv1 verifies)
__global__ __launch_bounds__(256) void k_conv2f(
    const float* __restrict__ y1, const float* __restrict__ cat,
    const float* __restrict__ Wf, const float* __restrict__ bf,
    float* __restrict__ Qout)
{
    int blk = blockIdx.x;
    int wt = blk & 7;   blk >>= 3;
    int ht = blk & 7;   blk >>= 3;
    int g  = blk & 3;   blk >>= 2;
    int b  = blk;
    int tid = threadIdx.x;
    int tw = tid & 31, th = tid >> 5;
    int rb = th * 4;
    int h = ht * 32 + rb, w = wt * 32 + tw;

    __shared__ __align__(16) float tile[2][34][36];
    __shared__ __align__(16) float wb[2][16][12];

    float accA[16], accB[16], accC[16], accD[16];
    #pragma unroll
    for (int j = 0; j < 16; ++j) {
        float bb = bf[g * 16 + j];
        accA[j] = bb; accB[j] = bb; accC[j] = bb; accD[j] = bb;
    }

    const float* yg = y1 + ((size_t)b * 256 + g * 64) * 65536;
    const float* catp = cat + ((size_t)b * 256 + g * 64) * 65536
                            + (size_t)h * 256 + w;
    const float* wfg = Wf + (size_t)(g * 64) * 192;
    int h0 = ht * 32 - 1, w0 = wt * 32 - 1;

    int soff[5]; int slds[5]; bool sin[5];
    #pragma unroll
    for (int s = 0; s < 5; ++s) {
        int idx = tid + 256 * s;
        int r = idx / 34, c = idx - r * 34;
        bool v = idx < 1156;
        int hh = h0 + r, ww = w0 + c;
        sin[s]  = v && (unsigned)hh < 256u && (unsigned)ww < 256u;
        soff[s] = hh * 256 + ww;
        slds[s] = v ? (r * 36 + c) : (33 * 36 + 35);
    }
    bool wvld = tid < 192;   // 16 j x 12
    float t[5], wv, cv0, cv1, cv2, cv3, ncv0, ncv1, ncv2, ncv3;
    float* tile0 = &tile[0][0][0];

    {   // prologue ic=0
        #pragma unroll
        for (int s = 0; s < 5; ++s) {
            t[s] = sin[s] ? yg[soff[s]] : 0.f;
            tile0[slds[s]] = t[s];
        }
        if (wvld) (&wb[0][0][0])[tid] = wfg[tid];
        cv0 = catp[0]; cv1 = catp[256]; cv2 = catp[512]; cv3 = catp[768];
    }
    __syncthreads();

    int cur = 0;
    for (int ic = 0; ic < 64; ++ic) {
        bool pf = (ic + 1 < 64);
        if (pf) {
            const float* plane = yg + (size_t)(ic + 1) * 65536;
            #pragma unroll
            for (int s = 0; s < 5; ++s) t[s] = sin[s] ? plane[soff[s]] : 0.f;
            wv = wvld ? wfg[(size_t)(ic + 1) * 192 + tid] : 0.f;
            const float* cp = catp + (size_t)(ic + 1) * 65536;
            ncv0 = cp[0]; ncv1 = cp[256]; ncv2 = cp[512]; ncv3 = cp[768];
        }
        float xr[6][3];
        #pragma unroll
        for (int rr = 0; rr < 6; ++rr)
            #pragma unroll
            for (int cc = 0; cc < 3; ++cc)
                xr[rr][cc] = tile[cur][rb + rr][tw + cc];
        #pragma unroll
        for (int j = 0; j < 16; ++j) {
            float4 wa = *(const float4*)&wb[cur][j][0];
            float4 wc = *(const float4*)&wb[cur][j][4];
            float4 wd = *(const float4*)&wb[cur][j][8];  // x=w8, y=pws
            float s0 = accA[j], s1 = accB[j], s2 = accC[j], s3 = accD[j];
            s0 = fmaf(wa.x, xr[0][0], s0); s1 = fmaf(wa.x, xr[1][0], s1);
            s2 = fmaf(wa.x, xr[2][0], s2); s3 = fmaf(wa.x, xr[3][0], s3);
            s0 = fmaf(wa.y, xr[0][1], s0); s1 = fmaf(wa.y, xr[1][1], s1);
            s2 = fmaf(wa.y, xr[2][1], s2); s3 = fmaf(wa.y, xr[3][1], s3);
            s0 = fmaf(wa.z, xr[0][2], s0); s1 = fmaf(wa.z, xr[1][2], s1);
            s2 = fmaf(wa.z, xr[2][2], s2); s3 = fmaf(wa.z, xr[3][2], s3);
            s0 = fmaf(wa.w, xr[1][0], s0); s1 = fmaf(wa.w, xr[2][0], s1);
            s2 = fmaf(wa.w, xr[3][0], s2); s3 = fmaf(wa.w, xr[4][0], s3);
            s0 = fmaf(wc.x, xr[1][1], s0); s1 = fmaf(wc.x, xr[2][1], s1);
            s2 = fmaf(wc.x, xr[3][1], s2); s3 = fmaf(wc.x, xr[4][1], s3);
            s0 = fmaf(wc.y, xr[1][2], s0); s1 = fmaf(wc.y, xr[2][2], s1);
            s2 = fmaf(wc.y, xr[3][2], s2); s3 = fmaf(wc.y, xr[4][2], s3);
            s0 = fmaf(wc.z, xr[2][0], s0); s1 = fmaf(wc.z, xr[3][0], s1);
            s2 = fmaf(wc.z, xr[4][0], s2); s3 = fmaf(wc.z, xr[5][0], s3);
            s0 = fmaf(wc.w, xr[2][1], s0); s1 = fmaf(wc.w, xr[3][1], s1);
            s2 = fmaf(wc.w, xr[4][1], s2); s3 = fmaf(wc.w, xr[5][1], s3);
            s0 = fmaf(wd.x, xr[2][2], s0); s1 = fmaf(wd.x, xr[3][2], s1);
            s2 = fmaf(wd.x, xr[4][2], s2); s3 = fmaf(wd.x, xr[5][2], s3);
            s0 = fmaf(wd.y, cv0, s0);      s1 = fmaf(wd.y, cv1, s1);
            s2 = fmaf(wd.y, cv2, s2);      s3 = fmaf(wd.y, cv3, s3);
            accA[j] = s0; accB[j] = s1; accC[j] = s2; accD[j] = s3;
        }
        if (pf) {
            float* tn = &tile[cur ^ 1][0][0];
            #pragma unroll
            for (int s = 0; s < 5; ++s) tn[slds[s]] = t[s];
            if (wvld) (&wb[cur ^ 1][0][0])[tid] = wv;
            cv0 = ncv0; cv1 = ncv1; cv2 = ncv2; cv3 = ncv3;
        }
        __syncthreads();
        cur ^= 1;
    }

    float* qp = Qout + ((size_t)b * 64 + g * 16) * 65536 + (size_t)h * 256 + w;
    #pragma unroll
    for (int j = 0; j < 16; ++j) {
        qp[(size_t)j * 65536 +   0] = accA[j];
        qp[(size_t)j * 65536 + 256] = accB[j];
        qp[(size_t)j * 65536 + 512] = accC[j];
        qp[(size_t)j * 65536 + 768] = accD[j];
    }
}

// Horizontal disparity gathers, output in [b,h,w,c] layout (flat-index ready).
__global__ __launch_bounds__(256) void k_gather(
    const float* __restrict__ Kb, const float* __restrict__ Qb,
    const float* __restrict__ xr, const float* __restrict__ xl,
    const int* __restrict__ dl, const int* __restrict__ dr,
    float* __restrict__ GK, float* __restrict__ GQ,
    float* __restrict__ Gxr, float* __restrict__ Gxl)
{
    int blk = blockIdx.x;
    int h = blk & 255; blk >>= 8;
    int b = blk & 1;   blk >>= 1;
    int sel = blk;
    const float* src; float* dst; const int* dd; int r2l;
    if (sel == 0)      { src = Kb; dst = GK;  dd = dl; r2l = 1; }
    else if (sel == 1) { src = Qb; dst = GQ;  dd = dr; r2l = 0; }
    else if (sel == 2) { src = xr; dst = Gxr; dd = dl; r2l = 1; }
    else               { src = xl; dst = Gxl; dd = dr; r2l = 0; }
    const int* drow = dd + ((size_t)b * 256 + h) * 256;
    const float* sp = src + (size_t)b * 4194304 + h * 256;
    float* dp = dst + ((size_t)b * 256 + h) * 16384;
    int tid = threadIdx.x;
    for (int i = tid; i < 16384; i += 256) {
        int w = i >> 6, cc = i & 63;
        int d = drow[w];
        int wi = r2l ? (w - d < 0 ? 0 : w - d) : (w + d > 255 ? 255 : w + d);
        dp[i] = sp[(size_t)cc * 65536 + wi];
    }
}

// Per-window attention: score = patchA @ centered(sel)^T, softmax, @ x_sel,
// unpatchify + masked residual. One block per (dir, b, hn, wn).
__global__ __launch_bounds__(256) void k_attn(
    const float* __restrict__ Qb, const float* __restrict__ Kb,
    const float* __restrict__ GK, const float* __restrict__ GQ,
    const float* __restrict__ Gxr, const float* __restrict__ Gxl,
    const float* __restrict__ xl, const float* __restrict__ xr,
    const int* __restrict__ dl, const int* __restrict__ dr,
    float* __restrict__ out)
{
    int blk = blockIdx.x;
    int wn = blk & 31; blk >>= 5;
    int hn = blk & 31; blk >>= 5;
    int b  = blk & 1;  blk >>= 1;
    int dir = blk;  // 0: out_left, 1: out_right

    const float* Amat = dir ? Kb : Qb;
    const float* Bg   = dir ? GQ : GK;
    const float* Xg   = dir ? Gxl : Gxr;
    const float* base = dir ? xr : xl;
    const int*  dd    = dir ? dr : dl;
    float* op = out + (size_t)dir * 8388608;

    __shared__ float A[64][65];
    __shared__ float Bm[64][65];
    __shared__ float S[64][65];
    __shared__ float rowsum[64];
    __shared__ float pmean[8];

    int tid = threadIdx.x;
    size_t abase = (size_t)b * 4194304 + (size_t)(hn * 8) * 256 + wn * 8;
    for (int i = tid; i < 4096; i += 256) {
        int cc = i >> 6, p1 = i & 63;
        A[p1][cc] = Amat[abase + (size_t)cc * 65536 + (p1 >> 3) * 256 + (p1 & 7)];
    }
    size_t gbase = (size_t)b * 4194304 + hn * 2048 + wn * 8;
    for (int i = tid; i < 4096; i += 256) {
        int cc = i >> 6, p2 = i & 63;
        Bm[p2][cc] = Bg[gbase + (size_t)cc * 65536 + (p2 >> 3) * 256 + (p2 & 7)];
    }
    __syncthreads();
    if (tid < 64) {
        float s = 0.f;
        #pragma unroll 8
        for (int cc = 0; cc < 64; ++cc) s += Bm[tid][cc];
        rowsum[tid] = s;
    }
    __syncthreads();
    if (tid < 8) {
        float s = 0.f;
        #pragma unroll
        for (int q = 0; q < 8; ++q) s += rowsum[tid * 8 + q];
        pmean[tid] = s * (1.f / 512.f);
    }
    __syncthreads();
    for (int i = tid; i < 4096; i += 256) {
        int p2 = i >> 6, cc = i & 63;
        Bm[p2][cc] -= pmean[p2 >> 3];
    }
    __syncthreads();

    int tp = (tid >> 4) << 2;
    int tc = (tid & 15) << 2;
    {   // S = A @ Bm^T
        float accs[4][4] = {};
        for (int cc = 0; cc < 64; ++cc) {
            float av[4], bv[4];
            #pragma unroll
            for (int i = 0; i < 4; ++i) av[i] = A[tp + i][cc];
            #pragma unroll
            for (int j = 0; j < 4; ++j) bv[j] = Bm[tc + j][cc];
            #pragma unroll
            for (int i = 0; i < 4; ++i)
                #pragma unroll
                for (int j = 0; j < 4; ++j)
                    accs[i][j] = fmaf(av[i], bv[j], accs[i][j]);
        }
        #pragma unroll
        for (int i = 0; i < 4; ++i)
            #pragma unroll
            for (int j = 0; j < 4; ++j)
                S[tp + i][tc + j] = accs[i][j];
    }
    __syncthreads();
    if (tid < 64) {
        float m = -3.0e38f;
        #pragma unroll 8
        for (int j = 0; j < 64; ++j) m = fmaxf(m, S[tid][j]);
        float ssum = 0.f;
        #pragma unroll 8
        for (int j = 0; j < 64; ++j) {
            float e = __expf(S[tid][j] - m);
            S[tid][j] = e; ssum += e;
        }
        float inv = 1.f / ssum;
        #pragma unroll 8
        for (int j = 0; j < 64; ++j) S[tid][j] *= inv;
    }
    __syncthreads();
    for (int i = tid; i < 4096; i += 256) {
        int cc = i >> 6, p2 = i & 63;
        Bm[p2][cc] = Xg[gbase + (size_t)cc * 65536 + (p2 >> 3) * 256 + (p2 & 7)];
    }
    __syncthreads();
    {   // out = S @ X, unpatchify, masked residual
        float accs[4][4] = {};
        for (int p2 = 0; p2 < 64; ++p2) {
            float sv[4], xv[4];
            #pragma unroll
            for (int i = 0; i < 4; ++i) sv[i] = S[tp + i][p2];
            #pragma unroll
            for (int j = 0; j < 4; ++j) xv[j] = Bm[p2][tc + j];
            #pragma unroll
            for (int i = 0; i < 4; ++i)
                #pragma unroll
                for (int j = 0; j < 4; ++j)
                    accs[i][j] = fmaf(sv[i], xv[j], accs[i][j]);
        }
        #pragma unroll
        for (int i = 0; i < 4; ++i) {
            int p1 = tp + i;
            int h1 = hn * 8 + (p1 >> 3), w1 = wn * 8 + (p1 & 7);
            int d = dd[(size_t)b * 65536 + h1 * 256 + w1];
            float msk = dir ? ((w1 + d <= 255) ? 1.f : 0.f)
                            : ((w1 - d >= 0) ? 1.f : 0.f);
            #pragma unroll
            for (int j = 0; j < 4; ++j) {
                int ch = tc + j;
                size_t o = (size_t)b * 4194304 + (size_t)ch * 65536 + (size_t)h1 * 256 + w1;
                op[o] = fmaf(accs[i][j], msk, base[o]);
            }
        }
    }
}

extern "C" void kernel_launch(void* const* d_in, const int* in_sizes, int n_in,
                              void* d_out, int out_size, void* d_ws, size_t ws_size,
                              hipStream_t stream) {
    (void)in_sizes; (void)n_in; (void)out_size; (void)ws_size;
    const float* x_left  = (const float*)d_in[0];
    const float* x_right = (const float*)d_in[1];
    const float* cat_l   = (const float*)d_in[2];
    const float* cat_r   = (const float*)d_in[3];
    const int*   d_left  = (const int*)d_in[4];
    const int*   d_right = (const int*)d_in[5];
    const float* gamma   = (const float*)d_in[6];
    const float* beta    = (const float*)d_in[7];
    const float* rb_w1   = (const float*)d_in[8];
    const float* rb_b1   = (const float*)d_in[9];
    const float* rb_w2   = (const float*)d_in[10];
    const float* rb_b2   = (const float*)d_in[11];
    const float* bq_w    = (const float*)d_in[12];
    const float* bq_b    = (const float*)d_in[13];
    const float* bs_w    = (const float*)d_in[14];
    const float* bs_b    = (const float*)d_in[15];
    float* out = (float*)d_out;
    float* ws  = (float*)d_ws;

    float* y1    = ws;               // 33,554,432 floats (reused per side)
    float* GK    = ws;               // alias after y1 is dead
    float* GQ    = ws + 8388608;
    float* Gxr   = ws + 16777216;
    float* Gxl   = ws + 25165824;
    float* Qb    = ws + 33554432;
    float* Kb    = ws + 41943040;
    float* stats = ws + 50331648;    // [2][scale 256 | shift 256]
    float* WfQ = Kb;                 // fold scratch in dead Kb region
    float* bfQ = Kb + 49152;
    float* WfK = out;                // d_out scratch until k_attn
    float* bfK = out + 49152;

    k_bnstats<<<512, 256, 0, stream>>>(cat_l, cat_r, gamma, beta, stats);
    k_fold<<<32, 256, 0, stream>>>(rb_w2, rb_b2, bq_w, bq_b, bs_w, bs_b, stats,
                                   WfQ, bfQ, WfK, bfK);
    k_conv1<<<2048, 256, 0, stream>>>(cat_l, stats, rb_w1, rb_b1, y1);
    k_conv2f<<<512, 256, 0, stream>>>(y1, cat_l, WfQ, bfQ, Qb);
    k_conv1<<<2048, 256, 0, stream>>>(cat_r, stats + 512, rb_w1, rb_b1, y1);
    k_conv2f<<<512, 256, 0, stream>>>(y1, cat_r, WfK, bfK, Kb);
    k_gather<<<2048, 256, 0, stream>>>(Kb, Qb, x_right, x_left, d_left, d_right,
                                       GK, GQ, Gxr, Gxl);
    k_attn<<<4096, 256, 0, stream>>>(Qb, Kb, GK, GQ, Gxr, Gxl,
                                     x_left, x_right, d_left, d_right, out);
}